// Round 1
// baseline (21104.720 us; speedup 1.0000x reference)
//
#include <hip/hip_runtime.h>
#include <hip/hip_bf16.h>
#include <math.h>

#define NAB 128
#define NG 50

__device__ __forceinline__ float sspf(float x) {
  // softplus(x) - ln(2), numerically stable
  float t = __expf(-fabsf(x));
  return fmaxf(x, 0.0f) + __logf(1.0f + t) - 0.69314718055994531f;
}

// C[M,128] = A[M,128] @ W[128,128] (+ bias) (optional ssp epilogue)
// Block: 128 threads, 32 rows per block. W (64KB) + A-tile (16KB) in LDS.
__global__ __launch_bounds__(128)
void gemm128(const float* __restrict__ A, const float* __restrict__ W,
             const float* __restrict__ bias, float* __restrict__ C,
             int M, int do_ssp) {
  __shared__ float Wl[128 * 128];
  __shared__ float Al[32 * 128];
  const int tid = threadIdx.x;
  const int r0 = blockIdx.x * 32;
  const int rows = min(32, M - r0);

  // stage W (row-major, 16384 floats = 4096 float4)
  {
    const float4* W4 = (const float4*)W;
    float4* Wl4 = (float4*)Wl;
#pragma unroll
    for (int k = 0; k < 32; ++k) Wl4[tid + k * 128] = W4[tid + k * 128];
  }
  // stage A tile (coalesced row-major copy)
  {
    const float4* A4 = (const float4*)(A + (size_t)r0 * NAB);
    float4* Al4 = (float4*)Al;
    for (int f = tid; f < rows * 32; f += 128) Al4[f] = A4[f];
  }
  __syncthreads();

  const int c = tid & 31;   // columns 4c..4c+3
  const int gq = tid >> 5;  // rows gq*8 .. gq*8+7
  float acc[8][4];
#pragma unroll
  for (int j = 0; j < 8; ++j) {
    acc[j][0] = 0.f; acc[j][1] = 0.f; acc[j][2] = 0.f; acc[j][3] = 0.f;
  }
  const float4* Wl4 = (const float4*)Wl;
  for (int i = 0; i < 128; i += 4) {
    float4 w0 = Wl4[(i + 0) * 32 + c];
    float4 w1 = Wl4[(i + 1) * 32 + c];
    float4 w2 = Wl4[(i + 2) * 32 + c];
    float4 w3 = Wl4[(i + 3) * 32 + c];
#pragma unroll
    for (int j = 0; j < 8; ++j) {
      float4 av = *(const float4*)&Al[(gq * 8 + j) * 128 + i];
      acc[j][0] += av.x * w0.x + av.y * w1.x + av.z * w2.x + av.w * w3.x;
      acc[j][1] += av.x * w0.y + av.y * w1.y + av.z * w2.y + av.w * w3.y;
      acc[j][2] += av.x * w0.z + av.y * w1.z + av.z * w2.z + av.w * w3.z;
      acc[j][3] += av.x * w0.w + av.y * w1.w + av.z * w2.w + av.w * w3.w;
    }
  }
  float4 bv = make_float4(0.f, 0.f, 0.f, 0.f);
  if (bias) bv = *(const float4*)&bias[4 * c];
#pragma unroll
  for (int j = 0; j < 8; ++j) {
    int row = gq * 8 + j;
    if (row < rows) {
      float4 o;
      o.x = acc[j][0] + bv.x;
      o.y = acc[j][1] + bv.y;
      o.z = acc[j][2] + bv.z;
      o.w = acc[j][3] + bv.w;
      if (do_ssp) { o.x = sspf(o.x); o.y = sspf(o.y); o.z = sspf(o.z); o.w = sspf(o.w); }
      *(float4*)&C[(size_t)(r0 + row) * NAB + 4 * c] = o;
    }
  }
}

// One edge per thread. Weights read wave-uniformly (scalar loads).
// h[50] staged through LDS for the runtime-indexed second stage.
__global__ __launch_bounds__(256)
void edge_kernel(const float* __restrict__ e, const int* __restrict__ a,
                 const float* __restrict__ rf,
                 const float* __restrict__ W1, const float* __restrict__ b1,
                 const float* __restrict__ W2, const float* __restrict__ b2,
                 float* __restrict__ agg, int E) {
  __shared__ float hl[256 * NG];
  const int tid = threadIdx.x;
  const int eid = blockIdx.x * 256 + tid;
  if (eid >= E) return;

  const int src = a[2 * eid + 0];
  const int dst = a[2 * eid + 1];
  const float ev = e[eid];

  constexpr float width = 5.0f / 49.0f;
  constexpr float coeff = -0.5f / (width * width);

  // stage 1: h = ssp(g @ W_df1 + b_df1), g computed on the fly
  float h[NG];
#pragma unroll
  for (int j = 0; j < NG; ++j) h[j] = b1[j];
  for (int i = 0; i < NG; ++i) {
    float d = ev - i * width;
    float gi = __expf(coeff * d * d);
    const float* w = W1 + i * NG;
#pragma unroll
    for (int j = 0; j < NG; ++j) h[j] = __fmaf_rn(gi, w[j], h[j]);
  }
#pragma unroll
  for (int j = 0; j < NG; ++j) hl[tid * NG + j] = sspf(h[j]);

  const float* rs = rf + (size_t)src * NAB;
  const float* rd = rf + (size_t)dst * NAB;
  float* as_ = agg + (size_t)src * NAB;
  float* ad_ = agg + (size_t)dst * NAB;

  // stage 2: ef chunkwise; multiply with gathered rf rows; atomic scatter
  for (int kk = 0; kk < NAB; kk += 16) {
    float ef[16];
#pragma unroll
    for (int t = 0; t < 16; ++t) ef[t] = b2[kk + t];
    for (int i = 0; i < NG; ++i) {
      float hi = hl[tid * NG + i];
      const float* w = W2 + i * NAB + kk;
#pragma unroll
      for (int t = 0; t < 16; ++t) ef[t] = __fmaf_rn(hi, w[t], ef[t]);
    }
    float sarr[16], darr[16];
#pragma unroll
    for (int q = 0; q < 4; ++q) {
      float4 v = *(const float4*)(rs + kk + 4 * q);
      sarr[4 * q + 0] = v.x; sarr[4 * q + 1] = v.y; sarr[4 * q + 2] = v.z; sarr[4 * q + 3] = v.w;
      float4 u = *(const float4*)(rd + kk + 4 * q);
      darr[4 * q + 0] = u.x; darr[4 * q + 1] = u.y; darr[4 * q + 2] = u.z; darr[4 * q + 3] = u.w;
    }
#pragma unroll
    for (int t = 0; t < 16; ++t) {
      unsafeAtomicAdd(ad_ + kk + t, sarr[t] * ef[t]);  // m1 = rf[src]*ef -> agg[dst]
      unsafeAtomicAdd(as_ + kk + t, darr[t] * ef[t]);  // m2 = rf[dst]*ef -> agg[src]
    }
  }
}

extern "C" void kernel_launch(void* const* d_in, const int* in_sizes, int n_in,
                              void* d_out, int out_size, void* d_ws, size_t ws_size,
                              hipStream_t stream) {
  const float* r     = (const float*)d_in[0];
  const float* e     = (const float*)d_in[1];
  const int*   a     = (const int*)d_in[2];
  const float* W_df1 = (const float*)d_in[3];
  const float* b_df1 = (const float*)d_in[4];
  const float* W_df2 = (const float*)d_in[5];
  const float* b_df2 = (const float*)d_in[6];
  const float* W_af  = (const float*)d_in[7];
  const float* W_d1  = (const float*)d_in[8];
  const float* b_d1  = (const float*)d_in[9];
  const float* W_d2  = (const float*)d_in[10];
  const float* b_d2  = (const float*)d_in[11];

  const int N = in_sizes[0] / NAB;
  const int E = in_sizes[1];

  float* rf  = (float*)d_ws;                 // N*128 floats
  float* agg = rf + (size_t)N * NAB;         // N*128 floats
  float* t1  = rf;                           // reuse rf region after edge pass

  const int gblocks = (N + 31) / 32;

  // 1) rf = r @ W_af
  gemm128<<<gblocks, 128, 0, stream>>>(r, W_af, nullptr, rf, N, 0);
  // 2) agg = 0
  hipMemsetAsync(agg, 0, (size_t)N * NAB * sizeof(float), stream);
  // 3) fused edge MLP + gather + atomic scatter
  edge_kernel<<<(E + 255) / 256, 256, 0, stream>>>(e, a, rf, W_df1, b_df1,
                                                   W_df2, b_df2, agg, E);
  // 4) t1 = ssp(agg @ W_d1 + b_d1)
  gemm128<<<gblocks, 128, 0, stream>>>(agg, W_d1, b_d1, t1, N, 1);
  // 5) out = t1 @ W_d2 + b_d2
  gemm128<<<gblocks, 128, 0, stream>>>(t1, W_d2, b_d2, (float*)d_out, N, 0);
}

// Round 2
// 1037.173 us; speedup vs baseline: 20.3483x; 20.3483x over previous
//
#include <hip/hip_runtime.h>
#include <hip/hip_bf16.h>
#include <math.h>

#define NAB 128
#define NG 50
#define TK 4096   // ef interpolation table size (TK*128*4B = 2.1 MB, L2-resident)

__device__ __forceinline__ float sspf(float x) {
  // softplus(x) - ln(2), numerically stable
  float t = __expf(-fabsf(x));
  return fmaxf(x, 0.0f) + __logf(1.0f + t) - 0.69314718055994531f;
}

// ---------------------------------------------------------------------------
// C[M,128] = A[M,128] @ W[128,128] (+ bias) (optional ssp epilogue)
// Block: 128 threads, 32 rows per block. W (64KB) + A-tile (16KB) in LDS.
__global__ __launch_bounds__(128)
void gemm128(const float* __restrict__ A, const float* __restrict__ W,
             const float* __restrict__ bias, float* __restrict__ C,
             int M, int do_ssp) {
  __shared__ float Wl[128 * 128];
  __shared__ float Al[32 * 128];
  const int tid = threadIdx.x;
  const int r0 = blockIdx.x * 32;
  const int rows = min(32, M - r0);

  {
    const float4* W4 = (const float4*)W;
    float4* Wl4 = (float4*)Wl;
#pragma unroll
    for (int k = 0; k < 32; ++k) Wl4[tid + k * 128] = W4[tid + k * 128];
  }
  {
    const float4* A4 = (const float4*)(A + (size_t)r0 * NAB);
    float4* Al4 = (float4*)Al;
    for (int f = tid; f < rows * 32; f += 128) Al4[f] = A4[f];
  }
  __syncthreads();

  const int c = tid & 31;
  const int gq = tid >> 5;
  float acc[8][4];
#pragma unroll
  for (int j = 0; j < 8; ++j) {
    acc[j][0] = 0.f; acc[j][1] = 0.f; acc[j][2] = 0.f; acc[j][3] = 0.f;
  }
  const float4* Wl4 = (const float4*)Wl;
  for (int i = 0; i < 128; i += 4) {
    float4 w0 = Wl4[(i + 0) * 32 + c];
    float4 w1 = Wl4[(i + 1) * 32 + c];
    float4 w2 = Wl4[(i + 2) * 32 + c];
    float4 w3 = Wl4[(i + 3) * 32 + c];
#pragma unroll
    for (int j = 0; j < 8; ++j) {
      float4 av = *(const float4*)&Al[(gq * 8 + j) * 128 + i];
      acc[j][0] += av.x * w0.x + av.y * w1.x + av.z * w2.x + av.w * w3.x;
      acc[j][1] += av.x * w0.y + av.y * w1.y + av.z * w2.y + av.w * w3.y;
      acc[j][2] += av.x * w0.z + av.y * w1.z + av.z * w2.z + av.w * w3.z;
      acc[j][3] += av.x * w0.w + av.y * w1.w + av.z * w2.w + av.w * w3.w;
    }
  }
  float4 bv = make_float4(0.f, 0.f, 0.f, 0.f);
  if (bias) bv = *(const float4*)&bias[4 * c];
#pragma unroll
  for (int j = 0; j < 8; ++j) {
    int row = gq * 8 + j;
    if (row < rows) {
      float4 o;
      o.x = acc[j][0] + bv.x;
      o.y = acc[j][1] + bv.y;
      o.z = acc[j][2] + bv.z;
      o.w = acc[j][3] + bv.w;
      if (do_ssp) { o.x = sspf(o.x); o.y = sspf(o.y); o.z = sspf(o.z); o.w = sspf(o.w); }
      *(float4*)&C[(size_t)(r0 + row) * NAB + 4 * c] = o;
    }
  }
}

// ---------------------------------------------------------------------------
// Build T[k][f] = ef(e_k) on a uniform grid e_k = k * CUTOFF/(TK-1).
// One block (128 threads) per grid point.
__global__ __launch_bounds__(128)
void build_table(const float* __restrict__ W1, const float* __restrict__ b1,
                 const float* __restrict__ W2, const float* __restrict__ b2,
                 float* __restrict__ T) {
  __shared__ float g[NG];
  __shared__ float h[NG];
  const int k = blockIdx.x;
  const int tid = threadIdx.x;
  constexpr float width = 5.0f / 49.0f;
  constexpr float coeff = -0.5f / (width * width);
  const float ev = (float)k * (5.0f / (float)(TK - 1));

  if (tid < NG) {
    float d = ev - tid * width;
    g[tid] = __expf(coeff * d * d);
  }
  __syncthreads();
  if (tid < NG) {
    float acc = b1[tid];
#pragma unroll 10
    for (int i = 0; i < NG; ++i) acc = __fmaf_rn(g[i], W1[i * NG + tid], acc);
    h[tid] = sspf(acc);
  }
  __syncthreads();
  float acc = b2[tid];
#pragma unroll 10
  for (int i = 0; i < NG; ++i) acc = __fmaf_rn(h[i], W2[i * NAB + tid], acc);
  T[(size_t)k * NAB + tid] = acc;
}

// ---------------------------------------------------------------------------
// Counting sort of 3.2M half-edges by target node.
__global__ __launch_bounds__(256)
void hist_kernel(const int* __restrict__ a, int* __restrict__ counts, int E) {
  int i = blockIdx.x * 256 + threadIdx.x;
  if (i >= 2 * E) return;
  int tgt = (i < E) ? a[2 * i + 1] : a[2 * (i - E)];
  atomicAdd(&counts[tgt], 1);
}

__global__ __launch_bounds__(1024)
void scan_kernel(const int* __restrict__ counts, int* __restrict__ offs,
                 int* __restrict__ cursor, int n) {
  __shared__ int sums[1024];
  const int t = threadIdx.x;
  const int C = (n + 1023) / 1024;
  const int b = t * C;
  const int e = min(b + C, n);
  int s = 0;
  for (int i = b; i < e; ++i) s += counts[i];
  sums[t] = s;
  __syncthreads();
  for (int d = 1; d < 1024; d <<= 1) {
    int v = (t >= d) ? sums[t - d] : 0;
    __syncthreads();
    sums[t] += v;
    __syncthreads();
  }
  int run = (t == 0) ? 0 : sums[t - 1];
  for (int i = b; i < e; ++i) {
    offs[i] = run;
    cursor[i] = run;
    run += counts[i];
  }
  if (t == 1023) offs[n] = run;
}

__global__ __launch_bounds__(256)
void scatter_kernel(const int* __restrict__ a, const float* __restrict__ e,
                    int* __restrict__ cursor, int* __restrict__ srows,
                    float* __restrict__ evals, int E) {
  int i = blockIdx.x * 256 + threadIdx.x;
  if (i >= 2 * E) return;
  int edge, tgt, src;
  if (i < E) {
    edge = i; src = a[2 * i]; tgt = a[2 * i + 1];
  } else {
    edge = i - E; tgt = a[2 * edge]; src = a[2 * edge + 1];
  }
  int pos = atomicAdd(&cursor[tgt], 1);
  srows[pos] = src;
  evals[pos] = e[edge];
}

// ---------------------------------------------------------------------------
// Pull-mode aggregation: one block (128 threads = one feature each) per node.
// agg[n][f] = sum over incident half-edges j of rf[srows[j]][f] * lerp(T, evals[j])[f]
__global__ __launch_bounds__(128)
void pull_kernel(const int* __restrict__ offs, const int* __restrict__ srows,
                 const float* __restrict__ evals, const float* __restrict__ rf,
                 const float* __restrict__ T, float* __restrict__ agg) {
  const int n = blockIdx.x;
  const int f = threadIdx.x;
  const int beg = offs[n];
  const int end = offs[n + 1];
  const float scale = (float)(TK - 1) / 5.0f;
  float acc = 0.f;
  int j = beg;
  for (; j + 4 <= end; j += 4) {
#pragma unroll
    for (int u = 0; u < 4; ++u) {
      int sr = srows[j + u];
      float ev = evals[j + u];
      float x = ev * scale;
      int k = (int)x;
      k = max(0, min(k, TK - 2));
      float fr = x - (float)k;
      float t0 = T[(size_t)k * NAB + f];
      float t1 = T[(size_t)(k + 1) * NAB + f];
      float rv = rf[(size_t)sr * NAB + f];
      acc = __fmaf_rn(rv, __fmaf_rn(fr, t1 - t0, t0), acc);
    }
  }
  for (; j < end; ++j) {
    int sr = srows[j];
    float ev = evals[j];
    float x = ev * scale;
    int k = (int)x;
    k = max(0, min(k, TK - 2));
    float fr = x - (float)k;
    float t0 = T[(size_t)k * NAB + f];
    float t1 = T[(size_t)(k + 1) * NAB + f];
    float rv = rf[(size_t)sr * NAB + f];
    acc = __fmaf_rn(rv, __fmaf_rn(fr, t1 - t0, t0), acc);
  }
  agg[(size_t)n * NAB + f] = acc;
}

// ---------------------------------------------------------------------------
extern "C" void kernel_launch(void* const* d_in, const int* in_sizes, int n_in,
                              void* d_out, int out_size, void* d_ws, size_t ws_size,
                              hipStream_t stream) {
  const float* r     = (const float*)d_in[0];
  const float* e     = (const float*)d_in[1];
  const int*   a     = (const int*)d_in[2];
  const float* W_df1 = (const float*)d_in[3];
  const float* b_df1 = (const float*)d_in[4];
  const float* W_df2 = (const float*)d_in[5];
  const float* b_df2 = (const float*)d_in[6];
  const float* W_af  = (const float*)d_in[7];
  const float* W_d1  = (const float*)d_in[8];
  const float* b_d1  = (const float*)d_in[9];
  const float* W_d2  = (const float*)d_in[10];
  const float* b_d2  = (const float*)d_in[11];

  const int N = in_sizes[0] / NAB;
  const int E = in_sizes[1];
  const int H = 2 * E;  // half-edges

  // workspace layout
  float* rf     = (float*)d_ws;                       // N*128
  float* agg    = rf + (size_t)N * NAB;               // N*128
  float* T      = agg + (size_t)N * NAB;              // TK*128
  float* evals  = T + (size_t)TK * NAB;               // 2E
  int*   srows  = (int*)(evals + H);                  // 2E
  int*   counts = srows + H;                          // N
  int*   offs   = counts + N;                         // N+1
  int*   cursor = offs + N + 1;                       // N
  float* t1     = rf;                                 // reuse rf after pull

  const int gblocks = (N + 31) / 32;
  const int hblocks = (H + 255) / 256;

  // 1) ef interpolation table
  build_table<<<TK, 128, 0, stream>>>(W_df1, b_df1, W_df2, b_df2, T);
  // 2) rf = r @ W_af
  gemm128<<<gblocks, 128, 0, stream>>>(r, W_af, nullptr, rf, N, 0);
  // 3) counting sort of half-edges by target node
  hipMemsetAsync(counts, 0, (size_t)N * sizeof(int), stream);
  hist_kernel<<<hblocks, 256, 0, stream>>>(a, counts, E);
  scan_kernel<<<1, 1024, 0, stream>>>(counts, offs, cursor, N);
  scatter_kernel<<<hblocks, 256, 0, stream>>>(a, e, cursor, srows, evals, E);
  // 4) pull-mode aggregation (no atomics)
  pull_kernel<<<N, 128, 0, stream>>>(offs, srows, evals, rf, T, agg);
  // 5) t1 = ssp(agg @ W_d1 + b_d1)
  gemm128<<<gblocks, 128, 0, stream>>>(agg, W_d1, b_d1, t1, N, 1);
  // 6) out = t1 @ W_d2 + b_d2
  gemm128<<<gblocks, 128, 0, stream>>>(t1, W_d2, b_d2, (float*)d_out, N, 0);
}

// Round 3
// 982.263 us; speedup vs baseline: 21.4858x; 1.0559x over previous
//
#include <hip/hip_runtime.h>
#include <hip/hip_bf16.h>
#include <math.h>

#define NAB 128
#define NG 50
#define TK 1024   // ef interpolation table size (TK*128*4B = 512 KB, per-XCD-L2-resident)

__device__ __forceinline__ float sspf(float x) {
  // softplus(x) - ln(2), numerically stable
  float t = __expf(-fabsf(x));
  return fmaxf(x, 0.0f) + __logf(1.0f + t) - 0.69314718055994531f;
}

// ---------------------------------------------------------------------------
// C[M,128] = A[M,128] @ W[128,128] (+ bias) (optional ssp epilogue)
__global__ __launch_bounds__(128)
void gemm128(const float* __restrict__ A, const float* __restrict__ W,
             const float* __restrict__ bias, float* __restrict__ C,
             int M, int do_ssp) {
  __shared__ float Wl[128 * 128];
  __shared__ float Al[32 * 128];
  const int tid = threadIdx.x;
  const int r0 = blockIdx.x * 32;
  const int rows = min(32, M - r0);

  {
    const float4* W4 = (const float4*)W;
    float4* Wl4 = (float4*)Wl;
#pragma unroll
    for (int k = 0; k < 32; ++k) Wl4[tid + k * 128] = W4[tid + k * 128];
  }
  {
    const float4* A4 = (const float4*)(A + (size_t)r0 * NAB);
    float4* Al4 = (float4*)Al;
    for (int f = tid; f < rows * 32; f += 128) Al4[f] = A4[f];
  }
  __syncthreads();

  const int c = tid & 31;
  const int gq = tid >> 5;
  float acc[8][4];
#pragma unroll
  for (int j = 0; j < 8; ++j) {
    acc[j][0] = 0.f; acc[j][1] = 0.f; acc[j][2] = 0.f; acc[j][3] = 0.f;
  }
  const float4* Wl4 = (const float4*)Wl;
  for (int i = 0; i < 128; i += 4) {
    float4 w0 = Wl4[(i + 0) * 32 + c];
    float4 w1 = Wl4[(i + 1) * 32 + c];
    float4 w2 = Wl4[(i + 2) * 32 + c];
    float4 w3 = Wl4[(i + 3) * 32 + c];
#pragma unroll
    for (int j = 0; j < 8; ++j) {
      float4 av = *(const float4*)&Al[(gq * 8 + j) * 128 + i];
      acc[j][0] += av.x * w0.x + av.y * w1.x + av.z * w2.x + av.w * w3.x;
      acc[j][1] += av.x * w0.y + av.y * w1.y + av.z * w2.y + av.w * w3.y;
      acc[j][2] += av.x * w0.z + av.y * w1.z + av.z * w2.z + av.w * w3.z;
      acc[j][3] += av.x * w0.w + av.y * w1.w + av.z * w2.w + av.w * w3.w;
    }
  }
  float4 bv = make_float4(0.f, 0.f, 0.f, 0.f);
  if (bias) bv = *(const float4*)&bias[4 * c];
#pragma unroll
  for (int j = 0; j < 8; ++j) {
    int row = gq * 8 + j;
    if (row < rows) {
      float4 o;
      o.x = acc[j][0] + bv.x;
      o.y = acc[j][1] + bv.y;
      o.z = acc[j][2] + bv.z;
      o.w = acc[j][3] + bv.w;
      if (do_ssp) { o.x = sspf(o.x); o.y = sspf(o.y); o.z = sspf(o.z); o.w = sspf(o.w); }
      *(float4*)&C[(size_t)(r0 + row) * NAB + 4 * c] = o;
    }
  }
}

// ---------------------------------------------------------------------------
// Build T[k][f] = ef(e_k) on a uniform grid e_k = k * CUTOFF/(TK-1).
__global__ __launch_bounds__(128)
void build_table(const float* __restrict__ W1, const float* __restrict__ b1,
                 const float* __restrict__ W2, const float* __restrict__ b2,
                 float* __restrict__ T) {
  __shared__ float g[NG];
  __shared__ float h[NG];
  const int k = blockIdx.x;
  const int tid = threadIdx.x;
  constexpr float width = 5.0f / 49.0f;
  constexpr float coeff = -0.5f / (width * width);
  const float ev = (float)k * (5.0f / (float)(TK - 1));

  if (tid < NG) {
    float d = ev - tid * width;
    g[tid] = __expf(coeff * d * d);
  }
  __syncthreads();
  if (tid < NG) {
    float acc = b1[tid];
#pragma unroll 10
    for (int i = 0; i < NG; ++i) acc = __fmaf_rn(g[i], W1[i * NG + tid], acc);
    h[tid] = sspf(acc);
  }
  __syncthreads();
  float acc = b2[tid];
#pragma unroll 10
  for (int i = 0; i < NG; ++i) acc = __fmaf_rn(h[i], W2[i * NAB + tid], acc);
  T[(size_t)k * NAB + tid] = acc;
}

// ---------------------------------------------------------------------------
// Counting sort of 3.2M half-edges by target node.
__global__ __launch_bounds__(256)
void hist_kernel(const int* __restrict__ a, int* __restrict__ counts, int E) {
  int i = blockIdx.x * 256 + threadIdx.x;
  if (i >= 2 * E) return;
  int tgt = (i < E) ? a[2 * i + 1] : a[2 * (i - E)];
  atomicAdd(&counts[tgt], 1);
}

__global__ __launch_bounds__(1024)
void scan_kernel(const int* __restrict__ counts, int* __restrict__ offs,
                 int* __restrict__ cursor, int n) {
  __shared__ int sums[1024];
  const int t = threadIdx.x;
  const int C = (n + 1023) / 1024;
  const int b = t * C;
  const int e = min(b + C, n);
  int s = 0;
  for (int i = b; i < e; ++i) s += counts[i];
  sums[t] = s;
  __syncthreads();
  for (int d = 1; d < 1024; d <<= 1) {
    int v = (t >= d) ? sums[t - d] : 0;
    __syncthreads();
    sums[t] += v;
    __syncthreads();
  }
  int run = (t == 0) ? 0 : sums[t - 1];
  for (int i = b; i < e; ++i) {
    offs[i] = run;
    cursor[i] = run;
    run += counts[i];
  }
  if (t == 1023) offs[n] = run;
}

// Scatter (src, e) packed as one 8B int2 per half-edge — one dirtied line, not two.
__global__ __launch_bounds__(256)
void scatter_kernel(const int* __restrict__ a, const float* __restrict__ e,
                    int* __restrict__ cursor, int2* __restrict__ pairs, int E) {
  int i = blockIdx.x * 256 + threadIdx.x;
  if (i >= 2 * E) return;
  int edge, tgt, src;
  if (i < E) {
    edge = i; src = a[2 * i]; tgt = a[2 * i + 1];
  } else {
    edge = i - E; tgt = a[2 * edge]; src = a[2 * edge + 1];
  }
  int pos = atomicAdd(&cursor[tgt], 1);
  pairs[pos] = make_int2(src, __float_as_int(e[edge]));
}

// ---------------------------------------------------------------------------
// Pull-mode aggregation: one block (128 threads = one feature each) per node.
__global__ __launch_bounds__(128)
void pull_kernel(const int* __restrict__ offs, const int2* __restrict__ pairs,
                 const float* __restrict__ rf, const float* __restrict__ T,
                 float* __restrict__ agg) {
  const int n = blockIdx.x;
  const int f = threadIdx.x;
  const int beg = offs[n];
  const int end = offs[n + 1];
  const float scale = (float)(TK - 1) / 5.0f;
  float acc = 0.f;
  int j = beg;
  for (; j + 8 <= end; j += 8) {
    float t0v[8], t1v[8], rv[8], frv[8];
#pragma unroll
    for (int u = 0; u < 8; ++u) {
      int2 p = pairs[j + u];
      float x = __int_as_float(p.y) * scale;
      int k = (int)x;
      k = max(0, min(k, TK - 2));
      frv[u] = x - (float)k;
      t0v[u] = T[(size_t)k * NAB + f];
      t1v[u] = T[(size_t)(k + 1) * NAB + f];
      rv[u]  = rf[(size_t)p.x * NAB + f];
    }
#pragma unroll
    for (int u = 0; u < 8; ++u)
      acc = __fmaf_rn(rv[u], __fmaf_rn(frv[u], t1v[u] - t0v[u], t0v[u]), acc);
  }
  for (; j < end; ++j) {
    int2 p = pairs[j];
    float x = __int_as_float(p.y) * scale;
    int k = (int)x;
    k = max(0, min(k, TK - 2));
    float fr = x - (float)k;
    float t0 = T[(size_t)k * NAB + f];
    float t1 = T[(size_t)(k + 1) * NAB + f];
    float rv = rf[(size_t)p.x * NAB + f];
    acc = __fmaf_rn(rv, __fmaf_rn(fr, t1 - t0, t0), acc);
  }
  agg[(size_t)n * NAB + f] = acc;
}

// ---------------------------------------------------------------------------
extern "C" void kernel_launch(void* const* d_in, const int* in_sizes, int n_in,
                              void* d_out, int out_size, void* d_ws, size_t ws_size,
                              hipStream_t stream) {
  const float* r     = (const float*)d_in[0];
  const float* e     = (const float*)d_in[1];
  const int*   a     = (const int*)d_in[2];
  const float* W_df1 = (const float*)d_in[3];
  const float* b_df1 = (const float*)d_in[4];
  const float* W_df2 = (const float*)d_in[5];
  const float* b_df2 = (const float*)d_in[6];
  const float* W_af  = (const float*)d_in[7];
  const float* W_d1  = (const float*)d_in[8];
  const float* b_d1  = (const float*)d_in[9];
  const float* W_d2  = (const float*)d_in[10];
  const float* b_d2  = (const float*)d_in[11];

  const int N = in_sizes[0] / NAB;
  const int E = in_sizes[1];
  const int H = 2 * E;  // half-edges

  // workspace layout
  float* rf     = (float*)d_ws;                       // N*128
  float* agg    = rf + (size_t)N * NAB;               // N*128
  float* T      = agg + (size_t)N * NAB;              // TK*128
  int2*  pairs  = (int2*)(T + (size_t)TK * NAB);      // 2E (8B each)
  int*   counts = (int*)(pairs + H);                  // N
  int*   offs   = counts + N;                         // N+1
  int*   cursor = offs + N + 1;                       // N
  float* t1     = rf;                                 // reuse rf after pull

  const int gblocks = (N + 31) / 32;
  const int hblocks = (H + 255) / 256;

  // 1) ef interpolation table
  build_table<<<TK, 128, 0, stream>>>(W_df1, b_df1, W_df2, b_df2, T);
  // 2) rf = r @ W_af
  gemm128<<<gblocks, 128, 0, stream>>>(r, W_af, nullptr, rf, N, 0);
  // 3) counting sort of half-edges by target node
  hipMemsetAsync(counts, 0, (size_t)N * sizeof(int), stream);
  hist_kernel<<<hblocks, 256, 0, stream>>>(a, counts, E);
  scan_kernel<<<1, 1024, 0, stream>>>(counts, offs, cursor, N);
  scatter_kernel<<<hblocks, 256, 0, stream>>>(a, e, cursor, pairs, E);
  // 4) pull-mode aggregation (no atomics)
  pull_kernel<<<N, 128, 0, stream>>>(offs, pairs, rf, T, agg);
  // 5) t1 = ssp(agg @ W_d1 + b_d1)
  gemm128<<<gblocks, 128, 0, stream>>>(agg, W_d1, b_d1, t1, N, 1);
  // 6) out = t1 @ W_d2 + b_d2
  gemm128<<<gblocks, 128, 0, stream>>>(t1, W_d2, b_d2, (float*)d_out, N, 0);
}